// Round 12
// baseline (2104.518 us; speedup 1.0000x reference)
//
#include <hip/hip_runtime.h>
#include <hip/hip_bf16.h>

// ---------------------------------------------------------------------------
// CrossAttentionBlock — R12: single persistent fused kernel.
// R11 analysis: attn 46.7us; ~112us spread over 3 small kernels + gaps, each
// latency/ramp-bound (floors ~3-12us). Fix = structural: ONE launch, phases
// {proj, upsample, attn, epi} separated by software grid barriers
// (device-scope atomics + threadfence; counters zeroed via hipMemsetAsync).
// Co-residency by construction: grid 1152, demand 4.5-5 blocks/CU,
// capacity = min(LDS 160/24.6=6, VGPR<=102 (launch_bounds(256,5)) -> 5,
// waves 8) = 5. Attn: 2304 units / 1152 blocks = 2 (chunk-major, same rows
// -> Q frags loaded once; occupancy 31->~56%). Epi rewritten LDS-free.
// Phase bodies = R10/R11-proven forms (proj block-split scalar weights;
// commuted upsample; LDS-staged swizzled K/V attn w/ ones-MFMA + fp16
// partials).
// ---------------------------------------------------------------------------

constexpr int B   = 2;
constexpr int N   = 9216;   // 96*96
constexpr int E   = 64;
constexpr int CO  = 32;
constexpr int CT  = 64;
constexpr int SPLIT  = 16;
constexpr int MCHUNK = N / SPLIT;        // 576
constexpr int KVBLK  = 64;
constexpr int ROUNDS = MCHUNK / KVBLK;   // 9
constexpr int GRID   = 1152;

constexpr int KP_BLK = 288;  // K proj units
constexpr int VP_BLK = 288;  // V proj units
constexpr int QP_BLK = 32;   // Qs proj units

typedef _Float16 f16x8 __attribute__((ext_vector_type(8)));
typedef _Float16 f16x4 __attribute__((ext_vector_type(4)));
typedef float    f32x4 __attribute__((ext_vector_type(4)));
typedef unsigned int u32;

#define MFMA(a, b, c) __builtin_amdgcn_mfma_f32_16x16x32_f16((a), (b), (c), 0, 0, 0)

// async global->LDS, 16B per lane, dest = base + lane*16 (wave-linear)
#define GLOAD16(gsrc, ldst)                                                     \
  __builtin_amdgcn_global_load_lds(                                             \
      (const __attribute__((address_space(1))) u32*)(gsrc),                     \
      (__attribute__((address_space(3))) u32*)(ldst), 16, 0, 0)

// exp(s/8) == exp2(s * SC); SC folded into the small Q projection.
#define SC 0.18033688011112042f

// Software grid barrier. Safe because all GRID blocks are co-resident by
// construction. Agent-scope release/acquire fences handle cross-XCD L2.
__device__ __forceinline__ void grid_barrier(unsigned* cnt) {
  __syncthreads();
  if (threadIdx.x == 0) {
    __threadfence();   // release: write-back XCD L2
    __hip_atomic_fetch_add(cnt, 1u, __ATOMIC_RELEASE, __HIP_MEMORY_SCOPE_AGENT);
    while (__hip_atomic_load(cnt, __ATOMIC_ACQUIRE, __HIP_MEMORY_SCOPE_AGENT)
           < (unsigned)GRID)
      __builtin_amdgcn_s_sleep(2);
    __threadfence();   // acquire: invalidate XCD L2
  }
  __syncthreads();
}

__global__ __launch_bounds__(256, 5) void fused_kernel(
    const float* __restrict__ xt,   // [B][64][32][32]
    const float* __restrict__ xo,   // [B][32][N]
    const float* __restrict__ qw, const float* __restrict__ qb,
    const float* __restrict__ kw, const float* __restrict__ kb,
    const float* __restrict__ vw, const float* __restrict__ vb,
    const float* __restrict__ ow, const float* __restrict__ gm,
    const float* __restrict__ bt, const float* __restrict__ mn,
    const float* __restrict__ vr,
    float* __restrict__ out,
    _Float16* __restrict__ Qd,      // [B][N][E]
    _Float16* __restrict__ Kd,      // [B][N][E]
    _Float16* __restrict__ Vtd,     // [B][CO][N]
    float* __restrict__ Qs,         // [B*1024][64]
    _Float16* __restrict__ OutWS,   // [SPLIT][B][N][CO] fp16
    float* __restrict__ SumWS,      // [SPLIT][B][N]
    unsigned* __restrict__ bars)
{
  __shared__ _Float16 Kl[2][KVBLK][64];   // 16 KB
  __shared__ _Float16 Vl[2][CO][KVBLK];   //  8 KB

  const int tid = threadIdx.x;
  const int bid = blockIdx.x;

  // ================= phase A: projections (608 active units) =================
  if (bid < KP_BLK) {
    const int p      = (bid >> 2) * 256 + tid;
    const int estart = (bid & 3) * 16;
    const int b = p / N, n = p % N;
    const float* xb = xo + (size_t)b * CO * N + n;
    float x[32];
#pragma unroll
    for (int c = 0; c < 32; ++c) x[c] = xb[(size_t)c * N];
    _Float16* Kp = Kd + (size_t)p * E + estart;
#pragma unroll 1
    for (int e0 = 0; e0 < 16; e0 += 8) {
      union { _Float16 h[8]; uint4 v; } pk;
#pragma unroll
      for (int j = 0; j < 8; ++j) {
        const int e = estart + e0 + j;
        float acc = kb[e];
#pragma unroll
        for (int c = 0; c < 32; ++c) acc += x[c] * kw[e * 32 + c];
        pk.h[j] = (_Float16)acc;
      }
      *(uint4*)(Kp + e0) = pk.v;
    }
  } else if (bid < KP_BLK + VP_BLK) {
    const int vbid   = bid - KP_BLK;
    const int p      = (vbid >> 2) * 256 + tid;
    const int ostart = (vbid & 3) * 8;
    const int b = p / N, n = p % N;
    const float* xb = xo + (size_t)b * CO * N + n;
    float x[32];
#pragma unroll
    for (int c = 0; c < 32; ++c) x[c] = xb[(size_t)c * N];
    _Float16* Vp = Vtd + (size_t)b * CO * N + n;
#pragma unroll 1
    for (int j = 0; j < 8; ++j) {
      const int o = ostart + j;
      float acc = vb[o];
#pragma unroll
      for (int c = 0; c < 32; ++c) acc += x[c] * vw[o * 32 + c];
      Vp[(size_t)o * N] = (_Float16)acc;
    }
  } else if (bid < KP_BLK + VP_BLK + QP_BLK) {
    const int qbid   = bid - KP_BLK - VP_BLK;
    const int pix    = (qbid >> 2) * 256 + tid;   // 0..2047
    const int estart = (qbid & 3) * 16;
    const int b = pix >> 10, p10 = pix & 1023;
    const float* xb = xt + (size_t)b * 64 * 1024 + p10;
    float x[64];
#pragma unroll
    for (int c = 0; c < 64; ++c) x[c] = xb[(size_t)c * 1024];
    float* Qp = Qs + (size_t)pix * 64 + estart;
#pragma unroll 1
    for (int e0 = 0; e0 < 16; e0 += 4) {
      f32x4 v;
#pragma unroll
      for (int j = 0; j < 4; ++j) {
        const int e = estart + e0 + j;
        float acc = qb[e];
#pragma unroll
        for (int c = 0; c < 64; ++c) acc += x[c] * qw[e * 64 + c];
        v[j] = acc * SC;
      }
      *(f32x4*)(Qp + e0) = v;
    }
  }

  grid_barrier(&bars[0]);

  // ================= phase B: bilinear upsample of Qs (288 active) ==========
  if (bid < 288) {
    const int t4 = bid * 256 + tid;
    const int p  = t4 >> 2;
    const int eq = t4 & 3;
    const int b = p / N, n = p % N;
    const int ho = n / 96, wo = n % 96;

    const float sh = (ho + 0.5f) * (1.0f / 3.0f) - 0.5f;
    const float sw = (wo + 0.5f) * (1.0f / 3.0f) - 0.5f;
    int h0 = (int)floorf(sh); const float fh = sh - (float)h0;
    int w0 = (int)floorf(sw); const float fw = sw - (float)w0;
    int h1 = min(h0 + 1, 31); h0 = max(h0, 0);
    int w1 = min(w0 + 1, 31); w0 = max(w0, 0);

    const float c00 = (1.f - fh) * (1.f - fw), c01 = (1.f - fh) * fw;
    const float c10 = fh * (1.f - fw),         c11 = fh * fw;

    const float* Qb = Qs + (size_t)b * 1024 * 64 + eq * 16;
    const f32x4* q00 = (const f32x4*)(Qb + (h0 * 32 + w0) * 64);
    const f32x4* q01 = (const f32x4*)(Qb + (h0 * 32 + w1) * 64);
    const f32x4* q10 = (const f32x4*)(Qb + (h1 * 32 + w0) * 64);
    const f32x4* q11 = (const f32x4*)(Qb + (h1 * 32 + w1) * 64);

    union { _Float16 h[16]; uint4 v[2]; } pk;
#pragma unroll
    for (int j4 = 0; j4 < 4; ++j4) {
      const f32x4 a = q00[j4] * c00 + q01[j4] * c01 + q10[j4] * c10 + q11[j4] * c11;
#pragma unroll
      for (int i = 0; i < 4; ++i) pk.h[4 * j4 + i] = (_Float16)a[i];
    }
    _Float16* Qp = Qd + (size_t)p * E + eq * 16;
    *(uint4*)(Qp)     = pk.v[0];
    *(uint4*)(Qp + 8) = pk.v[1];
  }

  grid_barrier(&bars[32]);

  // ================= phase C: attention (all blocks, 2 chunks each) =========
  {
    const int wave = tid >> 6, lane = tid & 63;
    const int r16  = lane & 15, g = lane >> 4;
    const int t128   = bid % 144;
    const int chunk0 = bid / 144;           // 0..7; second unit = chunk0+8
    const int b      = t128 / 72;
    const int rowbase = (t128 % 72) * 128 + wave * 32;

    const _Float16* Qb = Qd  + ((size_t)b * N + rowbase) * E;
    const _Float16* Kb = Kd  + (size_t)b * N * E;
    const _Float16* Vb = Vtd + (size_t)b * CO * N;

    const int sub = lane >> 3, c8 = lane & 7;
    const int swz = 8 * (c8 ^ sub);          // halfs offset of swizzled 16B chunk

    // Q B-fragments: same rows for both chunks -> load once
    f16x8 qf[2][2];
#pragma unroll
    for (int rt = 0; rt < 2; ++rt)
#pragma unroll
      for (int ks = 0; ks < 2; ++ks)
        qf[rt][ks] = *(const f16x8*)(Qb + (rt * 16 + r16) * E + ks * 32 + g * 8);

    f16x8 onesf;
#pragma unroll
    for (int i = 0; i < 8; ++i) onesf[i] = (_Float16)1.0f;

    const int rsw   = (r16 & 7) << 4;
    const int kcol0 = ((0 * 64 + g * 16) ^ rsw) >> 1;
    const int kcol1 = ((1 * 64 + g * 16) ^ rsw) >> 1;

#pragma unroll 1
    for (int half = 0; half < 2; ++half) {
      const int chunk  = chunk0 + half * 8;
      const int mstart = chunk * MCHUNK;

      // prologue: stage round 0 into buf 0
      {
        const _Float16* gk = Kb + (size_t)(mstart + 16 * wave + sub) * E + swz;
        GLOAD16(gk,         &Kl[0][16 * wave][0]);
        GLOAD16(gk + 8 * E, &Kl[0][16 * wave + 8][0]);
        const _Float16* gv = Vb + (size_t)(8 * wave + sub) * N + mstart + swz;
        GLOAD16(gv,         &Vl[0][8 * wave][0]);
      }

      f32x4 oacc[2][2];
#pragma unroll
      for (int a = 0; a < 2; ++a)
#pragma unroll
        for (int c = 0; c < 2; ++c) oacc[a][c] = (f32x4){0.f, 0.f, 0.f, 0.f};
      f32x4 sacc[2];
      sacc[0] = (f32x4){0.f, 0.f, 0.f, 0.f};
      sacc[1] = (f32x4){0.f, 0.f, 0.f, 0.f};

      __syncthreads();

      int cur = 0;
      for (int r = 0; r < ROUNDS; ++r) {
        if (r + 1 < ROUNDS) {
          const int m0 = mstart + (r + 1) * KVBLK;
          const _Float16* gk = Kb + (size_t)(m0 + 16 * wave + sub) * E + swz;
          GLOAD16(gk,         &Kl[cur ^ 1][16 * wave][0]);
          GLOAD16(gk + 8 * E, &Kl[cur ^ 1][16 * wave + 8][0]);
          const _Float16* gv = Vb + (size_t)(8 * wave + sub) * N + m0 + swz;
          GLOAD16(gv,         &Vl[cur ^ 1][8 * wave][0]);
        }

#pragma unroll
        for (int it = 0; it < 2; ++it) {
          f16x8 kf[2][2];
#pragma unroll
          for (int mt = 0; mt < 2; ++mt) {
            const int krow = it * 32 + mt * 16 + r16;
            kf[mt][0] = *(const f16x8*)&Kl[cur][krow][kcol0];
            kf[mt][1] = *(const f16x8*)&Kl[cur][krow][kcol1];
          }
          union { f16x4 h[2]; f16x8 v; } vf[2];
#pragma unroll
          for (int ot = 0; ot < 2; ++ot) {
            const int vrow = ot * 16 + r16;
            const int v0 = ((it * 64 + 8 * g) ^ rsw) >> 1;
            const int v1 = ((it * 64 + 32 + 8 * g) ^ rsw) >> 1;
            vf[ot].h[0] = *(const f16x4*)&Vl[cur][vrow][v0];
            vf[ot].h[1] = *(const f16x4*)&Vl[cur][vrow][v1];
          }

#pragma unroll
          for (int rt = 0; rt < 2; ++rt) {
            f32x4 s0 = (f32x4){0.f, 0.f, 0.f, 0.f};
            f32x4 s1 = (f32x4){0.f, 0.f, 0.f, 0.f};
            s0 = MFMA(kf[0][0], qf[rt][0], s0);
            s0 = MFMA(kf[0][1], qf[rt][1], s0);
            s1 = MFMA(kf[1][0], qf[rt][0], s1);
            s1 = MFMA(kf[1][1], qf[rt][1], s1);

            float p0[4], p1[4];
#pragma unroll
            for (int i = 0; i < 4; ++i) {
              p0[i] = __builtin_amdgcn_exp2f(s0[i]);
              p1[i] = __builtin_amdgcn_exp2f(s1[i]);
            }

            union { unsigned u[4]; f16x8 v; } pb;
            pb.u[0] = __builtin_bit_cast(unsigned, __builtin_amdgcn_cvt_pkrtz(p0[0], p0[1]));
            pb.u[1] = __builtin_bit_cast(unsigned, __builtin_amdgcn_cvt_pkrtz(p0[2], p0[3]));
            pb.u[2] = __builtin_bit_cast(unsigned, __builtin_amdgcn_cvt_pkrtz(p1[0], p1[1]));
            pb.u[3] = __builtin_bit_cast(unsigned, __builtin_amdgcn_cvt_pkrtz(p1[2], p1[3]));

            oacc[rt][0] = MFMA(vf[0].v, pb.v, oacc[rt][0]);
            oacc[rt][1] = MFMA(vf[1].v, pb.v, oacc[rt][1]);
            sacc[rt]    = MFMA(onesf,   pb.v, sacc[rt]);
          }
        }

        __syncthreads();
        cur ^= 1;
      }

      _Float16* OW = OutWS + (size_t)(chunk * B + b) * N * CO;
      float*    SW = SumWS + (size_t)(chunk * B + b) * N;
#pragma unroll
      for (int rt = 0; rt < 2; ++rt) {
        const int n = rowbase + rt * 16 + r16;
        if (g == 0) SW[n] = sacc[rt][0];
#pragma unroll
        for (int ot = 0; ot < 2; ++ot) {
          uint2 pko;
          pko.x = __builtin_bit_cast(unsigned,
                    __builtin_amdgcn_cvt_pkrtz(oacc[rt][ot][0], oacc[rt][ot][1]));
          pko.y = __builtin_bit_cast(unsigned,
                    __builtin_amdgcn_cvt_pkrtz(oacc[rt][ot][2], oacc[rt][ot][3]));
          *(uint2*)(OW + (size_t)n * CO + ot * 16 + 4 * g) = pko;
        }
      }
    }
  }

  grid_barrier(&bars[64]);

  // ================= phase D: epilogue (288 active, LDS-free) ===============
  if (bid < 288) {
    const int nloc = tid & 63, grp = tid >> 6;   // grp: wave-uniform t-group
    const int pix  = bid * 64 + nloc;
    const int b    = pix / N, n = pix % N;

    float accf[CO];
#pragma unroll
    for (int o = 0; o < CO; ++o) accf[o] = 0.f;
    float ssum = 0.f;
#pragma unroll 1
    for (int sc = 0; sc < SPLIT; ++sc) {
      const f16x8* src = (const f16x8*)(OutWS + ((size_t)(sc * B + b) * N + n) * CO);
#pragma unroll
      for (int j = 0; j < 4; ++j) {
        const f16x8 c = src[j];
#pragma unroll
        for (int i = 0; i < 8; ++i) accf[j * 8 + i] += (float)c[i];
      }
      ssum += SumWS[(size_t)(sc * B + b) * N + n];
    }
    const float inv = 1.f / ssum;

#pragma unroll 1
    for (int i = 0; i < 16; ++i) {
      const int t = grp * 16 + i;   // wave-uniform -> scalar weight loads
      float acc2 = 0.f;
#pragma unroll
      for (int o = 0; o < CO; ++o) acc2 += accf[o] * ow[t * CO + o];
      const float scl = gm[t] * rsqrtf(vr[t] + 1e-5f);
      const float bia = bt[t] - mn[t] * scl;
      const float gv  = acc2 * inv * scl + bia;
      out[(size_t)(b * CT + t) * N + n] = fmaxf(gv, 0.f);
    }
  }
}

// ---------------------------------------------------------------------------
extern "C" void kernel_launch(void* const* d_in, const int* in_sizes, int n_in,
                              void* d_out, int out_size, void* d_ws, size_t ws_size,
                              hipStream_t stream) {
  const float* xt = (const float*)d_in[0];
  const float* xo = (const float*)d_in[1];
  const float* qw = (const float*)d_in[2];
  const float* qb = (const float*)d_in[3];
  const float* kw = (const float*)d_in[4];
  const float* kb = (const float*)d_in[5];
  const float* vw = (const float*)d_in[6];
  const float* vb = (const float*)d_in[7];
  const float* ow = (const float*)d_in[8];
  const float* gm = (const float*)d_in[9];
  const float* bt = (const float*)d_in[10];
  const float* mn = (const float*)d_in[11];
  const float* vr = (const float*)d_in[12];

  char* ws = (char*)d_ws;
  unsigned* bars = (unsigned*)ws;   ws += 512;
  _Float16* Qd  = (_Float16*)ws;    ws += (size_t)B * N * E * 2;        // 2.36 MB
  _Float16* Kd  = (_Float16*)ws;    ws += (size_t)B * N * E * 2;        // 2.36 MB
  _Float16* Vtd = (_Float16*)ws;    ws += (size_t)B * CO * N * 2;       // 1.18 MB
  float* Qs     = (float*)ws;       ws += (size_t)B * 1024 * 64 * 4;    // 0.52 MB
  _Float16* OutWS = (_Float16*)ws;  ws += (size_t)SPLIT * B * N * CO * 2; // 18.9 MB
  float* SumWS  = (float*)ws;                                           // 1.18 MB

  // zero the grid-barrier counters (graph-legal async memset, every call)
  hipMemsetAsync(bars, 0, 512, stream);

  fused_kernel<<<GRID, 256, 0, stream>>>(
      xt, xo, qw, qb, kw, kb, vw, vb, ow, gm, bt, mn, vr,
      (float*)d_out, Qd, Kd, Vtd, Qs, OutWS, SumWS, bars);
}

// Round 13
// 146.216 us; speedup vs baseline: 14.3932x; 14.3932x over previous
//
#include <hip/hip_runtime.h>
#include <hip/hip_bf16.h>

// ---------------------------------------------------------------------------
// CrossAttentionBlock — R13: revert R12's fused kernel (grid-barrier spin =
// 2073us, cross-XCD atomic polling). Back to R11 multi-kernel (158.75us),
// with the projections rebuilt as MFMA GEMMs (K-dim=32/64, one-two MFMA per
// tile) using the attn-proven fragment conventions + XOR-swizzled LDS
// transpose of x. proj ~35us (latency-bound scalar form) -> ~4us predicted.
// upsample_q / attn<16> / epi<16> byte-identical to R11.
// ---------------------------------------------------------------------------

constexpr int B   = 2;
constexpr int N   = 9216;   // 96*96
constexpr int E   = 64;
constexpr int CO  = 32;
constexpr int CT  = 64;
constexpr int KVBLK = 64;

constexpr int KV_BLKS = (B * N) / 128;   // 144 K/V GEMM blocks (128 px each)
constexpr int QS_BLKS = (B * 1024) / 128; // 16 Qs GEMM blocks

typedef _Float16 f16x8 __attribute__((ext_vector_type(8)));
typedef _Float16 f16x4 __attribute__((ext_vector_type(4)));
typedef float    f32x4 __attribute__((ext_vector_type(4)));
typedef unsigned int u32;

#define MFMA(a, b, c) __builtin_amdgcn_mfma_f32_16x16x32_f16((a), (b), (c), 0, 0, 0)

// async global->LDS, 16B per lane, dest = base + lane*16 (wave-linear)
#define GLOAD16(gsrc, ldst)                                                     \
  __builtin_amdgcn_global_load_lds(                                             \
      (const __attribute__((address_space(1))) u32*)(gsrc),                     \
      (__attribute__((address_space(3))) u32*)(ldst), 16, 0, 0)

#define PKRTZ(a, b) __builtin_bit_cast(unsigned, __builtin_amdgcn_cvt_pkrtz((a), (b)))

// exp(s/8) == exp2(s * SC); SC folded into the small Q projection.
#define SC 0.18033688011112042f

// ---------------------------------------------------------------------------
// Kernel 1: MFMA-GEMM projections.
//  blocks [0,144):   K + V from xo. Tile = 128 pixels. x^T staged in LDS
//                    (fp16, XOR-swizzled u32 words). K: D[e][p]=kw*x;
//                    V: D[o][p]=vw*x -> straight into transposed Vt.
//  blocks [144,160): Qs from xt at 32x32 (K-dim 64 -> 2 MFMA), f32 out.
// Fragment conventions identical to attn (A: r16=row, g*8 k-range;
// B: r16=col; D: col=r16, row=4g+i).
// ---------------------------------------------------------------------------
__global__ __launch_bounds__(256) void proj_gemm_kernel(
    const float* __restrict__ xo,   // [B][32][N]
    const float* __restrict__ kw, const float* __restrict__ kb,
    const float* __restrict__ vw, const float* __restrict__ vb,
    _Float16* __restrict__ K, _Float16* __restrict__ Vt,
    const float* __restrict__ xt,   // [B][64][32][32]
    const float* __restrict__ qw, const float* __restrict__ qb,
    float* __restrict__ Qs)         // [B*1024][64], (acc+qb)*SC
{
  __shared__ u32 Xl[128 * 32];   // 16 KB; K/V path uses rows of 16 words

  const int tid  = threadIdx.x;
  const int wave = tid >> 6, lane = tid & 63;
  const int r16  = lane & 15, g = lane >> 4;
  const int bid  = blockIdx.x;

  if (bid < KV_BLKS) {
    // ================= K/V projection GEMM =================
    const int p0 = bid * 128;            // global pixel base
    const int b  = p0 / N, n0 = p0 % N;  // 128 | 9216, no cross-batch block

    // stage x^T tile: [128 p][32 c] fp16, u32 word (c,c+1), swizzled w^(p&15)
    {
      const int p  = tid & 127;
      const int ch = tid >> 7;           // 0..1
#pragma unroll
      for (int cc = 0; cc < 8; ++cc) {
        const int c = cc * 4 + ch * 2;
        const float x0 = xo[((size_t)b * CO + c) * N + n0 + p];
        const float x1 = xo[((size_t)b * CO + c + 1) * N + n0 + p];
        Xl[p * 16 + ((c >> 1) ^ (p & 15))] = PKRTZ(x0, x1);
      }
    }
    __syncthreads();

    // each wave: 2 p-tiles (32 px), all 64 e (K) + 32 o (V)
    f16x8 xb[2];
#pragma unroll
    for (int pt = 0; pt < 2; ++pt) {
      const int p = (wave * 2 + pt) * 16 + r16;
      union { u32 u[4]; f16x8 v; } fr;
#pragma unroll
      for (int j = 0; j < 4; ++j)
        fr.u[j] = Xl[p * 16 + ((g * 4 + j) ^ r16)];
      xb[pt] = fr.v;
    }

    // K: 4 e-tiles x 2 p-tiles
#pragma unroll
    for (int et = 0; et < 4; ++et) {
      const float* kwe = kw + (size_t)(et * 16 + r16) * 32 + g * 8;
      const f32x4 w0 = *(const f32x4*)(kwe);
      const f32x4 w1 = *(const f32x4*)(kwe + 4);
      union { u32 u[4]; f16x8 v; } af;
      af.u[0] = PKRTZ(w0[0], w0[1]); af.u[1] = PKRTZ(w0[2], w0[3]);
      af.u[2] = PKRTZ(w1[0], w1[1]); af.u[3] = PKRTZ(w1[2], w1[3]);

      const int e0 = et * 16 + 4 * g;
      const float b0 = kb[e0], b1 = kb[e0 + 1], b2 = kb[e0 + 2], b3 = kb[e0 + 3];
#pragma unroll
      for (int pt = 0; pt < 2; ++pt) {
        f32x4 d = (f32x4){0.f, 0.f, 0.f, 0.f};
        d = MFMA(af.v, xb[pt], d);
        const int p = p0 + (wave * 2 + pt) * 16 + r16;
        uint2 pk;
        pk.x = PKRTZ(d[0] + b0, d[1] + b1);
        pk.y = PKRTZ(d[2] + b2, d[3] + b3);
        *(uint2*)(K + (size_t)p * E + e0) = pk;
      }
    }

    // V: 2 o-tiles x 2 p-tiles -> transposed store (coalesced over r16)
#pragma unroll
    for (int ot = 0; ot < 2; ++ot) {
      const float* vwo = vw + (size_t)(ot * 16 + r16) * 32 + g * 8;
      const f32x4 w0 = *(const f32x4*)(vwo);
      const f32x4 w1 = *(const f32x4*)(vwo + 4);
      union { u32 u[4]; f16x8 v; } af;
      af.u[0] = PKRTZ(w0[0], w0[1]); af.u[1] = PKRTZ(w0[2], w0[3]);
      af.u[2] = PKRTZ(w1[0], w1[1]); af.u[3] = PKRTZ(w1[2], w1[3]);

      const int o0 = ot * 16 + 4 * g;
      const float b0 = vb[o0], b1 = vb[o0 + 1], b2 = vb[o0 + 2], b3 = vb[o0 + 3];
#pragma unroll
      for (int pt = 0; pt < 2; ++pt) {
        f32x4 d = (f32x4){0.f, 0.f, 0.f, 0.f};
        d = MFMA(af.v, xb[pt], d);
        const int n = n0 + (wave * 2 + pt) * 16 + r16;
        Vt[((size_t)b * CO + o0)     * N + n] = (_Float16)(d[0] + b0);
        Vt[((size_t)b * CO + o0 + 1) * N + n] = (_Float16)(d[1] + b1);
        Vt[((size_t)b * CO + o0 + 2) * N + n] = (_Float16)(d[2] + b2);
        Vt[((size_t)b * CO + o0 + 3) * N + n] = (_Float16)(d[3] + b3);
      }
    }
  } else {
    // ================= Qs projection GEMM (32x32 grid, K-dim 64) ==========
    const int qbid = bid - KV_BLKS;
    const int qp0  = qbid * 128;          // 0..2047 base
    const int b    = qp0 >> 10, p10 = qp0 & 1023;

    // stage xt^T tile: [128 p][64 c] fp16, words swizzled w^(p&31)
    {
      const int p  = tid & 127;
      const int ch = tid >> 7;
#pragma unroll
      for (int cc = 0; cc < 16; ++cc) {
        const int c = cc * 4 + ch * 2;
        const float x0 = xt[(((size_t)b * 64 + c) << 10) + p10 + p];
        const float x1 = xt[(((size_t)b * 64 + c + 1) << 10) + p10 + p];
        Xl[p * 32 + ((c >> 1) ^ (p & 31))] = PKRTZ(x0, x1);
      }
    }
    __syncthreads();

    f16x8 xb[2][2];   // [p-tile][ks]
#pragma unroll
    for (int pt = 0; pt < 2; ++pt) {
      const int pl = (wave * 2 + pt) * 16 + r16;
#pragma unroll
      for (int ks = 0; ks < 2; ++ks) {
        union { u32 u[4]; f16x8 v; } fr;
#pragma unroll
        for (int j = 0; j < 4; ++j)
          fr.u[j] = Xl[pl * 32 + ((ks * 16 + g * 4 + j) ^ (pl & 31))];
        xb[pt][ks] = fr.v;
      }
    }

#pragma unroll
    for (int et = 0; et < 4; ++et) {
      union { u32 u[4]; f16x8 v; } af[2];
#pragma unroll
      for (int ks = 0; ks < 2; ++ks) {
        const float* qwe = qw + (size_t)(et * 16 + r16) * 64 + ks * 32 + g * 8;
        const f32x4 w0 = *(const f32x4*)(qwe);
        const f32x4 w1 = *(const f32x4*)(qwe + 4);
        af[ks].u[0] = PKRTZ(w0[0], w0[1]); af[ks].u[1] = PKRTZ(w0[2], w0[3]);
        af[ks].u[2] = PKRTZ(w1[0], w1[1]); af[ks].u[3] = PKRTZ(w1[2], w1[3]);
      }

      const int e0 = et * 16 + 4 * g;
      const f32x4 qb4 = {qb[e0], qb[e0 + 1], qb[e0 + 2], qb[e0 + 3]};
#pragma unroll
      for (int pt = 0; pt < 2; ++pt) {
        f32x4 d = (f32x4){0.f, 0.f, 0.f, 0.f};
        d = MFMA(af[0].v, xb[pt][0], d);
        d = MFMA(af[1].v, xb[pt][1], d);
        const int pix = qp0 + (wave * 2 + pt) * 16 + r16;
        *(f32x4*)(Qs + (size_t)pix * 64 + e0) = (d + qb4) * SC;
      }
    }
  }
}

// ---------------------------------------------------------------------------
// Kernel 2: bilinear 3x upsample of the PROJECTED field. (identical to R11)
// ---------------------------------------------------------------------------
__global__ __launch_bounds__(256) void upsample_q_kernel(
    const float* __restrict__ Qs,   // [B*1024][64], SC-scaled
    _Float16* __restrict__ Q)       // [B][N][E]
{
  const int tid = blockIdx.x * 256 + threadIdx.x;
  const int p   = tid >> 2;
  const int eq  = tid & 3;
  const int b   = p / N, n = p % N;
  const int ho  = n / 96, wo = n % 96;

  const float sh = (ho + 0.5f) * (1.0f / 3.0f) - 0.5f;
  const float sw = (wo + 0.5f) * (1.0f / 3.0f) - 0.5f;
  int h0 = (int)floorf(sh); const float fh = sh - (float)h0;
  int w0 = (int)floorf(sw); const float fw = sw - (float)w0;
  int h1 = min(h0 + 1, 31); h0 = max(h0, 0);
  int w1 = min(w0 + 1, 31); w0 = max(w0, 0);

  const float c00 = (1.f - fh) * (1.f - fw), c01 = (1.f - fh) * fw;
  const float c10 = fh * (1.f - fw),         c11 = fh * fw;

  const float* Qb = Qs + (size_t)b * 1024 * 64 + eq * 16;
  const f32x4* q00 = (const f32x4*)(Qb + (h0 * 32 + w0) * 64);
  const f32x4* q01 = (const f32x4*)(Qb + (h0 * 32 + w1) * 64);
  const f32x4* q10 = (const f32x4*)(Qb + (h1 * 32 + w0) * 64);
  const f32x4* q11 = (const f32x4*)(Qb + (h1 * 32 + w1) * 64);

  union { _Float16 h[16]; uint4 v[2]; } pk;
#pragma unroll
  for (int j4 = 0; j4 < 4; ++j4) {
    const f32x4 a = q00[j4] * c00 + q01[j4] * c01 + q10[j4] * c10 + q11[j4] * c11;
#pragma unroll
    for (int i = 0; i < 4; ++i) pk.h[4 * j4 + i] = (_Float16)a[i];
  }

  _Float16* Qp = Q + (size_t)p * E + eq * 16;
  *(uint4*)(Qp)     = pk.v[0];
  *(uint4*)(Qp + 8) = pk.v[1];
}

// ---------------------------------------------------------------------------
// Kernel 3: flash attention partials (identical to R11).
// ---------------------------------------------------------------------------
template<int SPLIT>
__global__ __launch_bounds__(256) void attn_kernel(
    const _Float16* __restrict__ Q,
    const _Float16* __restrict__ K,
    const _Float16* __restrict__ Vt,
    _Float16* __restrict__ OutWS,   // [SPLIT][B][N][CO] fp16
    float* __restrict__ SumWS)      // [SPLIT][B][N] f32
{
  constexpr int MCHUNK = N / SPLIT;
  constexpr int ROUNDS = MCHUNK / KVBLK;

  __shared__ _Float16 Kl[2][KVBLK][64];   // 16 KB
  __shared__ _Float16 Vl[2][CO][KVBLK];   //  8 KB

  const int tid  = threadIdx.x;
  const int wave = tid >> 6, lane = tid & 63;
  const int r16  = lane & 15, g = lane >> 4;

  const int work  = blockIdx.x;
  const int chunk = work & (SPLIT - 1);
  const int t128  = work / SPLIT;
  const int b     = t128 / 72;
  const int rowbase = (t128 % 72) * 128 + wave * 32;

  const _Float16* Qb = Q  + ((size_t)b * N + rowbase) * E;
  const _Float16* Kb = K  + (size_t)b * N * E;
  const _Float16* Vb = Vt + (size_t)b * CO * N;

  const int sub = lane >> 3, c8 = lane & 7;
  const int swz = 8 * (c8 ^ sub);

  const int mstart = chunk * MCHUNK;

  f16x8 qf[2][2];
#pragma unroll
  for (int rt = 0; rt < 2; ++rt)
#pragma unroll
    for (int ks = 0; ks < 2; ++ks)
      qf[rt][ks] = *(const f16x8*)(Qb + (rt * 16 + r16) * E + ks * 32 + g * 8);

  f16x8 onesf;
#pragma unroll
  for (int i = 0; i < 8; ++i) onesf[i] = (_Float16)1.0f;

  {
    const _Float16* gk = Kb + (size_t)(mstart + 16 * wave + sub) * E + swz;
    GLOAD16(gk,         &Kl[0][16 * wave][0]);
    GLOAD16(gk + 8 * E, &Kl[0][16 * wave + 8][0]);
    const _Float16* gv = Vb + (size_t)(8 * wave + sub) * N + mstart + swz;
    GLOAD16(gv,         &Vl[0][8 * wave][0]);
  }

  f32x4 oacc[2][2];
#pragma unroll
  for (int a = 0; a < 2; ++a)
#pragma unroll
    for (int c = 0; c < 2; ++c) oacc[a][c] = (f32x4){0.f, 0.f, 0.f, 0.f};
  f32x4 sacc[2];
  sacc[0] = (f32x4){0.f, 0.f, 0.f, 0.f};
  sacc[1] = (f32x4){0.f, 0.f, 0.f, 0.f};

  const int rsw   = (r16 & 7) << 4;
  const int kcol0 = ((0 * 64 + g * 16) ^ rsw) >> 1;
  const int kcol1 = ((1 * 64 + g * 16) ^ rsw) >> 1;

  __syncthreads();

  int cur = 0;
  for (int r = 0; r < ROUNDS; ++r) {
    if (r + 1 < ROUNDS) {
      const int m0 = mstart + (r + 1) * KVBLK;
      const _Float16* gk = Kb + (size_t)(m0 + 16 * wave + sub) * E + swz;
      GLOAD16(gk,         &Kl[cur ^ 1][16 * wave][0]);
      GLOAD16(gk + 8 * E, &Kl[cur ^ 1][16 * wave + 8][0]);
      const _Float16* gv = Vb + (size_t)(8 * wave + sub) * N + m0 + swz;
      GLOAD16(gv,         &Vl[cur ^ 1][8 * wave][0]);
    }

#pragma unroll
    for (int it = 0; it < 2; ++it) {
      f16x8 kf[2][2];
#pragma unroll
      for (int mt = 0; mt < 2; ++mt) {
        const int krow = it * 32 + mt * 16 + r16;
        kf[mt][0] = *(const f16x8*)&Kl[cur][krow][kcol0];
        kf[mt][1] = *(const f16x8*)&Kl[cur][krow][kcol1];
      }
      union { f16x4 h[2]; f16x8 v; } vf[2];
#pragma unroll
      for (int ot = 0; ot < 2; ++ot) {
        const int vrow = ot * 16 + r16;
        const int v0 = ((it * 64 + 8 * g) ^ rsw) >> 1;
        const int v1 = ((it * 64 + 32 + 8 * g) ^ rsw) >> 1;
        vf[ot].h[0] = *(const f16x4*)&Vl[cur][vrow][v0];
        vf[ot].h[1] = *(const f16x4*)&Vl[cur][vrow][v1];
      }

#pragma unroll
      for (int rt = 0; rt < 2; ++rt) {
        f32x4 s0 = (f32x4){0.f, 0.f, 0.f, 0.f};
        f32x4 s1 = (f32x4){0.f, 0.f, 0.f, 0.f};
        s0 = MFMA(kf[0][0], qf[rt][0], s0);
        s0 = MFMA(kf[0][1], qf[rt][1], s0);
        s1 = MFMA(kf[1][0], qf[rt][0], s1);
        s1 = MFMA(kf[1][1], qf[rt][1], s1);

        float p0[4], p1[4];
#pragma unroll
        for (int i = 0; i < 4; ++i) {
          p0[i] = __builtin_amdgcn_exp2f(s0[i]);
          p1[i] = __builtin_amdgcn_exp2f(s1[i]);
        }

        union { unsigned u[4]; f16x8 v; } pb;
        pb.u[0] = PKRTZ(p0[0], p0[1]);
        pb.u[1] = PKRTZ(p0[2], p0[3]);
        pb.u[2] = PKRTZ(p1[0], p1[1]);
        pb.u[3] = PKRTZ(p1[2], p1[3]);

        oacc[rt][0] = MFMA(vf[0].v, pb.v, oacc[rt][0]);
        oacc[rt][1] = MFMA(vf[1].v, pb.v, oacc[rt][1]);
        sacc[rt]    = MFMA(onesf,   pb.v, sacc[rt]);
      }
    }

    __syncthreads();
    cur ^= 1;
  }

  _Float16* OW = OutWS + (size_t)(chunk * B + b) * N * CO;
  float*    SW = SumWS + (size_t)(chunk * B + b) * N;
#pragma unroll
  for (int rt = 0; rt < 2; ++rt) {
    const int n = rowbase + rt * 16 + r16;
    if (g == 0) SW[n] = sacc[rt][0];
#pragma unroll
    for (int ot = 0; ot < 2; ++ot) {
      uint2 pko;
      pko.x = PKRTZ(oacc[rt][ot][0], oacc[rt][ot][1]);
      pko.y = PKRTZ(oacc[rt][ot][2], oacc[rt][ot][3]);
      *(uint2*)(OW + (size_t)n * CO + ot * 16 + 4 * g) = pko;
    }
  }
}

// ---------------------------------------------------------------------------
// Kernel 4: combine split-m partials (fp16), normalize, conv, BN, ReLU.
// (identical to R11)
// ---------------------------------------------------------------------------
template<int SPLIT>
__global__ __launch_bounds__(256) void epi_kernel(
    const _Float16* __restrict__ OutWS, const float* __restrict__ SumWS,
    const float* __restrict__ ow, const float* __restrict__ gamma,
    const float* __restrict__ beta, const float* __restrict__ mean,
    const float* __restrict__ var, float* __restrict__ out)
{
  __shared__ float part[4][64][33];
  __shared__ float psum[4][64];

  const int tid  = threadIdx.x;
  const int nloc = tid & 63, grp = tid >> 6;
  const int pix  = blockIdx.x * 64 + nloc;
  const int b    = pix / N, n = pix % N;

  float accf[32];
#pragma unroll
  for (int j = 0; j < 32; ++j) accf[j] = 0.f;
  float ssum = 0.f;
#pragma unroll
  for (int k = 0; k < SPLIT / 4; ++k) {
    const int sc = grp * (SPLIT / 4) + k;
    const f16x8* src = (const f16x8*)(OutWS + ((size_t)(sc * B + b) * N + n) * CO);
#pragma unroll
    for (int j = 0; j < 4; ++j) {
      const f16x8 c = src[j];
#pragma unroll
      for (int i = 0; i < 8; ++i) accf[j * 8 + i] += (float)c[i];
    }
    ssum += SumWS[(size_t)(sc * B + b) * N + n];
  }
#pragma unroll
  for (int j = 0; j < 32; ++j) part[grp][nloc][j] = accf[j];
  psum[grp][nloc] = ssum;
  __syncthreads();

  const float s = psum[0][nloc] + psum[1][nloc] + psum[2][nloc] + psum[3][nloc];
  const float inv = 1.f / s;
  float onr[CO];
#pragma unroll
  for (int o = 0; o < CO; ++o)
    onr[o] = (part[0][nloc][o] + part[1][nloc][o] +
              part[2][nloc][o] + part[3][nloc][o]) * inv;

#pragma unroll
  for (int i = 0; i < 16; ++i) {
    const int t = grp + 4 * i;
    float acc2 = 0.f;
#pragma unroll
    for (int o = 0; o < CO; ++o) acc2 += onr[o] * ow[t * CO + o];
    const float scl = gamma[t] * rsqrtf(var[t] + 1e-5f);
    const float bia = beta[t] - mean[t] * scl;
    const float gv  = acc2 * scl + bia;
    out[(size_t)(b * CT + t) * N + n] = fmaxf(gv, 0.f);
  }
}

// ---------------------------------------------------------------------------
extern "C" void kernel_launch(void* const* d_in, const int* in_sizes, int n_in,
                              void* d_out, int out_size, void* d_ws, size_t ws_size,
                              hipStream_t stream) {
  const float* xt = (const float*)d_in[0];
  const float* xo = (const float*)d_in[1];
  const float* qw = (const float*)d_in[2];
  const float* qb = (const float*)d_in[3];
  const float* kw = (const float*)d_in[4];
  const float* kb = (const float*)d_in[5];
  const float* vw = (const float*)d_in[6];
  const float* vb = (const float*)d_in[7];
  const float* ow = (const float*)d_in[8];
  const float* gm = (const float*)d_in[9];
  const float* bt = (const float*)d_in[10];
  const float* mn = (const float*)d_in[11];
  const float* vr = (const float*)d_in[12];

  char* ws = (char*)d_ws;
  _Float16* Qd  = (_Float16*)ws;  ws += (size_t)B * N * E * 2;    // 2.36 MB
  _Float16* Kd  = (_Float16*)ws;  ws += (size_t)B * N * E * 2;    // 2.36 MB
  _Float16* Vtd = (_Float16*)ws;  ws += (size_t)B * CO * N * 2;   // 1.18 MB
  float* Qs     = (float*)ws;     ws += (size_t)B * 1024 * 64 * 4;// 0.52 MB
  _Float16* OutWS = (_Float16*)ws;  // SPLIT*B*N*CO*2 (+SumWS f32)
  const size_t base   = (size_t)(ws - (char*)d_ws);
  const size_t need16 = base + (size_t)16 * B * N * (CO * 2 + 4); // ~26.6 MB

  proj_gemm_kernel<<<KV_BLKS + QS_BLKS, 256, 0, stream>>>(
      xo, kw, kb, vw, vb, Kd, Vtd, xt, qw, qb, Qs);
  upsample_q_kernel<<<(B * N * 4) / 256, 256, 0, stream>>>(Qs, Qd);

  if (ws_size >= need16) {
    float* SumWS = (float*)(OutWS + (size_t)16 * B * N * CO);
    attn_kernel<16><<<(N / 128) * B * 16, 256, 0, stream>>>(Qd, Kd, Vtd, OutWS, SumWS);
    epi_kernel<16><<<(B * N) / 64, 256, 0, stream>>>(OutWS, SumWS, ow, gm, bt, mn, vr,
                                                     (float*)d_out);
  } else {
    float* SumWS = (float*)(OutWS + (size_t)8 * B * N * CO);
    attn_kernel<8><<<(N / 128) * B * 8, 256, 0, stream>>>(Qd, Kd, Vtd, OutWS, SumWS);
    epi_kernel<8><<<(B * N) / 64, 256, 0, stream>>>(OutWS, SumWS, ow, gm, bt, mn, vr,
                                                    (float*)d_out);
  }
}